// Round 5
// baseline (294.059 us; speedup 1.0000x reference)
//
#include <hip/hip_runtime.h>
#include <math.h>

#define BB 64
#define PP 1024
#define DD 768
#define PS 16            // p-splits per batch; each block 64 rows, 16 per wave
#define NPART 64         // partials per batch = PS * 4 waves

// ---------------------------------------------------------------------------
// qw[d] = sum_e q[e] * W[e*D + d]  — grid (3, 32), atomicAdd combine
// ---------------------------------------------------------------------------
__global__ __launch_bounds__(256) void qw_kernel(const float* __restrict__ q,
                                                 const float* __restrict__ W,
                                                 float* __restrict__ qw) {
    int d  = blockIdx.x * 256 + threadIdx.x;
    int e0 = blockIdx.y * 24;
    float acc = 0.f;
#pragma unroll
    for (int i = 0; i < 24; ++i) {
        int e = e0 + i;
        acc += q[e] * W[(size_t)e * DD + d];
    }
    atomicAdd(&qw[d], acc);
}

// ---------------------------------------------------------------------------
// Fused single-pass pool, register-resident, barrier-free, 2-row pipelined.
// Wave owns 16 rows; rows i+1,i+2 loads are in flight while row i computes.
// ---------------------------------------------------------------------------
__global__ __launch_bounds__(256) void fused_kernel(const float* __restrict__ z,
                                                    const float* __restrict__ qw,
                                                    float* __restrict__ macc,
                                                    float* __restrict__ ml) {
    const float scale = 0.03608439182435161f;   // 1/sqrt(768)
    int b    = blockIdx.x;
    int ps   = blockIdx.y;
    int tid  = threadIdx.x;
    int wave = tid >> 6;
    int lane = tid & 63;

    const float4* qw4 = (const float4*)qw;
    float4 q0 = qw4[lane], q1 = qw4[lane + 64], q2 = qw4[lane + 128];

    int p0 = ps * 64 + wave * 16;
    const float4* zr = (const float4*)(z + ((size_t)b * PP + p0) * DD);

    // prefetch rows 0 and 1 (row stride = 192 float4)
    float4 c0 = zr[lane],       c1 = zr[lane + 64],       c2 = zr[lane + 128];
    float4 n0 = zr[192 + lane], n1 = zr[192 + lane + 64], n2 = zr[192 + lane + 128];

    float m = -INFINITY, l = 0.f;
    float4 a0 = {0.f, 0.f, 0.f, 0.f}, a1 = a0, a2 = a0;

#pragma unroll
    for (int i = 0; i < 16; ++i) {
        float4 t0, t1, t2;
        if (i < 14) {   // prefetch row i+2 BEFORE the dependent compute chain
            const float4* nx = zr + (size_t)(i + 2) * 192;
            t0 = nx[lane]; t1 = nx[lane + 64]; t2 = nx[lane + 128];
        }

        float dacc = c0.x * q0.x + c0.y * q0.y + c0.z * q0.z + c0.w * q0.w
                   + c1.x * q1.x + c1.y * q1.y + c1.z * q1.z + c1.w * q1.w
                   + c2.x * q2.x + c2.y * q2.y + c2.z * q2.z + c2.w * q2.w;
#pragma unroll
        for (int off = 32; off >= 1; off >>= 1)
            dacc += __shfl_xor(dacc, off, 64);

        float s     = dacc * scale;
        float mn    = fmaxf(m, s);
        float alpha = __expf(m - mn);   // first iter: exp(-inf)=0
        float e     = __expf(s - mn);
        l = l * alpha + e;
        a0.x = a0.x * alpha + e * c0.x;  a0.y = a0.y * alpha + e * c0.y;
        a0.z = a0.z * alpha + e * c0.z;  a0.w = a0.w * alpha + e * c0.w;
        a1.x = a1.x * alpha + e * c1.x;  a1.y = a1.y * alpha + e * c1.y;
        a1.z = a1.z * alpha + e * c1.z;  a1.w = a1.w * alpha + e * c1.w;
        a2.x = a2.x * alpha + e * c2.x;  a2.y = a2.y * alpha + e * c2.y;
        a2.z = a2.z * alpha + e * c2.z;  a2.w = a2.w * alpha + e * c2.w;
        m = mn;

        c0 = n0; c1 = n1; c2 = n2;
        n0 = t0; n1 = t1; n2 = t2;
    }

    int part = b * NPART + ps * 4 + wave;
    float4* ap4 = (float4*)(macc + (size_t)part * DD);
    ap4[lane] = a0; ap4[lane + 64] = a1; ap4[lane + 128] = a2;
    if (lane == 0) { ml[part * 2] = m; ml[part * 2 + 1] = l; }
}

// ---------------------------------------------------------------------------
// Combine 64 partials per batch:
//   M = max m_k; L = sum exp(m_k-M) l_k; out[d] = sum exp(m_k-M) acc_k[d] / L
// ---------------------------------------------------------------------------
__global__ __launch_bounds__(256) void reduce_kernel(const float* __restrict__ macc,
                                                     const float* __restrict__ ml,
                                                     float* __restrict__ out) {
    int b    = blockIdx.x;
    int tid  = threadIdx.x;
    int wave = tid >> 6;
    int lane = tid & 63;

    __shared__ float wts[NPART];
    __shared__ float Lsh;

    if (wave == 0) {
        float mk = ml[(b * NPART + lane) * 2];
        float lk = ml[(b * NPART + lane) * 2 + 1];
        float M = mk;
#pragma unroll
        for (int off = 32; off >= 1; off >>= 1) M = fmaxf(M, __shfl_xor(M, off, 64));
        float w = __expf(mk - M);
        float L = w * lk;
#pragma unroll
        for (int off = 32; off >= 1; off >>= 1) L += __shfl_xor(L, off, 64);
        wts[lane] = w;
        if (lane == 0) Lsh = L;
    }
    __syncthreads();

    float inv = 1.f / Lsh;
    const float* base = macc + (size_t)b * NPART * DD;
#pragma unroll
    for (int c = 0; c < 3; ++c) {
        int d = c * 256 + tid;
        float acc = 0.f;
#pragma unroll 8
        for (int k = 0; k < NPART; ++k) acc += wts[k] * base[(size_t)k * DD + d];
        out[b * DD + d] = acc * inv;
    }
}

// ---------------------------------------------------------------------------
extern "C" void kernel_launch(void* const* d_in, const int* in_sizes, int n_in,
                              void* d_out, int out_size, void* d_ws, size_t ws_size,
                              hipStream_t stream) {
    const float* z = (const float*)d_in[0];   // [B,P,D]
    const float* q = (const float*)d_in[1];   // [1,1,D]
    const float* W = (const float*)d_in[2];   // [D,D]
    float* out = (float*)d_out;               // [B,D]

    char* ws = (char*)d_ws;
    float* qw   = (float*)ws;                                  // 768 floats
    float* ml   = (float*)(ws + 4096);                         // 64*64*2 floats
    float* macc = (float*)(ws + 4096 + 65536);                 // 64*64*768 floats (12.6 MB)

    hipMemsetAsync(qw, 0, DD * sizeof(float), stream);
    dim3 qg(3, 32);
    qw_kernel<<<qg, 256, 0, stream>>>(q, W, qw);
    dim3 fg(BB, PS);
    fused_kernel<<<fg, 256, 0, stream>>>(z, qw, macc, ml);
    reduce_kernel<<<BB, 256, 0, stream>>>(macc, ml, out);
}

// Round 6
// 289.597 us; speedup vs baseline: 1.0154x; 1.0154x over previous
//
#include <hip/hip_runtime.h>
#include <math.h>

#define BB 64
#define PP 1024
#define DD 768
#define SS 8          // splits per batch: block covers 128 rows
#define TR 8          // rows per LDS tile
#define NT 16         // tiles per block = 128 / TR
#define NPART 32      // partials per batch = SS * 4 waves

// ---------------------------------------------------------------------------
// qw[d] = sum_e q[e] * W[e*D + d]  — grid (3, 32), atomicAdd combine
// ---------------------------------------------------------------------------
__global__ __launch_bounds__(256) void qw_kernel(const float* __restrict__ q,
                                                 const float* __restrict__ W,
                                                 float* __restrict__ qw) {
    int d  = blockIdx.x * 256 + threadIdx.x;
    int e0 = blockIdx.y * 24;
    float acc = 0.f;
#pragma unroll
    for (int i = 0; i < 24; ++i) {
        int e = e0 + i;
        acc += q[e] * W[(size_t)e * DD + d];
    }
    atomicAdd(&qw[d], acc);
}

// ---------------------------------------------------------------------------
// Fused single-pass pool. Block (b,split) does 128 rows as 16 tiles of 8.
// ONE barrier per tile; register dbuf: tile t+1 global loads are issued
// right after the barrier and waited only at the LDS write AFTER compute,
// so every wave keeps 6 KB in flight through its compute chain.
// Wave w owns rows 2w,2w+1 per tile (dot + online softmax + accumulate all
// wave-private). Writes one partial (m,l,acc[768]) per wave.
// ---------------------------------------------------------------------------
__global__ __launch_bounds__(256, 3) void fused_kernel(const float* __restrict__ z,
                                                       const float* __restrict__ qw,
                                                       float* __restrict__ macc,
                                                       float* __restrict__ ml) {
    const float scale = 0.03608439182435161f;   // 1/sqrt(768)
    __shared__ float4 buf[2][TR * DD / 4];      // 2 x 24 KB

    int b     = blockIdx.x;
    int split = blockIdx.y;
    int tid   = threadIdx.x;
    int wave  = tid >> 6;
    int lane  = tid & 63;

    const float4* qw4 = (const float4*)qw;
    float4 q0 = qw4[lane], q1 = qw4[lane + 64], q2 = qw4[lane + 128];

    // tile t occupies float4 range [t*1536, (t+1)*1536) of this block's span
    const float4* gz = (const float4*)(z + ((size_t)b * PP + split * 128) * DD);

    float m = -INFINITY, l = 0.f;
    float4 a0 = {0.f, 0.f, 0.f, 0.f}, a1 = a0, a2 = a0;

    // prologue: stage tile 0 into buf[0]
    {
        float4 tmp[6];
#pragma unroll
        for (int j = 0; j < 6; ++j) tmp[j] = gz[j * 256 + tid];
#pragma unroll
        for (int j = 0; j < 6; ++j) buf[0][j * 256 + tid] = tmp[j];
    }

    int r0 = wave * 2;   // wave's first row within each tile

    for (int t = 0; t < NT; ++t) {
        __syncthreads();   // publishes buf[t&1]; protects buf[(t+1)&1] overwrite

        // ---- issue next-tile loads BEFORE the compute chain ----
        float4 tmp[6];
        if (t + 1 < NT) {
#pragma unroll
            for (int j = 0; j < 6; ++j)
                tmp[j] = gz[(size_t)(t + 1) * 1536 + j * 256 + tid];
        }

        // ---- compute this wave's two rows from buf[t&1] ----
        const float4* bt = buf[t & 1];
#pragma unroll
        for (int rr = 0; rr < 2; ++rr) {
            const float4* rowp = bt + (r0 + rr) * 192;
            float4 z0 = rowp[lane], z1 = rowp[lane + 64], z2 = rowp[lane + 128];

            float d = z0.x * q0.x + z0.y * q0.y + z0.z * q0.z + z0.w * q0.w
                    + z1.x * q1.x + z1.y * q1.y + z1.z * q1.z + z1.w * q1.w
                    + z2.x * q2.x + z2.y * q2.y + z2.z * q2.z + z2.w * q2.w;
#pragma unroll
            for (int off = 32; off >= 1; off >>= 1)
                d += __shfl_xor(d, off, 64);

            float s     = d * scale;
            float mn    = fmaxf(m, s);
            float alpha = __expf(m - mn);    // first row: exp(-inf)=0
            float e     = __expf(s - mn);
            l = l * alpha + e;
            a0.x = a0.x * alpha + e * z0.x;  a0.y = a0.y * alpha + e * z0.y;
            a0.z = a0.z * alpha + e * z0.z;  a0.w = a0.w * alpha + e * z0.w;
            a1.x = a1.x * alpha + e * z1.x;  a1.y = a1.y * alpha + e * z1.y;
            a1.z = a1.z * alpha + e * z1.z;  a1.w = a1.w * alpha + e * z1.w;
            a2.x = a2.x * alpha + e * z2.x;  a2.y = a2.y * alpha + e * z2.y;
            a2.z = a2.z * alpha + e * z2.z;  a2.w = a2.w * alpha + e * z2.w;
            m = mn;
        }

        // ---- write next tile to the other buffer (vmcnt wait lands here) ----
        if (t + 1 < NT) {
#pragma unroll
            for (int j = 0; j < 6; ++j)
                buf[(t + 1) & 1][j * 256 + tid] = tmp[j];
        }
    }

    int part = (b * SS + split) * 4 + wave;
    float4* ap4 = (float4*)(macc + (size_t)part * DD);
    ap4[lane] = a0; ap4[lane + 64] = a1; ap4[lane + 128] = a2;
    if (lane == 0) { ml[part * 2] = m; ml[part * 2 + 1] = l; }
}

// ---------------------------------------------------------------------------
// Combine 32 partials per batch:
//   M = max m_k; L = sum exp(m_k-M) l_k; out[d] = sum exp(m_k-M) acc_k[d] / L
// ---------------------------------------------------------------------------
__global__ __launch_bounds__(256) void reduce_kernel(const float* __restrict__ macc,
                                                     const float* __restrict__ ml,
                                                     float* __restrict__ out) {
    int b    = blockIdx.x;
    int tid  = threadIdx.x;
    int wave = tid >> 6;
    int lane = tid & 63;

    __shared__ float wts[NPART];
    __shared__ float Lsh;

    if (wave == 0) {
        float mk = (lane < NPART) ? ml[(b * NPART + lane) * 2]     : -INFINITY;
        float lk = (lane < NPART) ? ml[(b * NPART + lane) * 2 + 1] : 0.f;
        float M = mk;
#pragma unroll
        for (int off = 32; off >= 1; off >>= 1) M = fmaxf(M, __shfl_xor(M, off, 64));
        float w = __expf(mk - M);            // exp(-inf - M) = 0 for pad lanes
        float L = w * lk;
#pragma unroll
        for (int off = 32; off >= 1; off >>= 1) L += __shfl_xor(L, off, 64);
        if (lane < NPART) wts[lane] = w;
        if (lane == 0) Lsh = L;
    }
    __syncthreads();

    float inv = 1.f / Lsh;
    const float* base = macc + (size_t)b * NPART * DD;
#pragma unroll
    for (int c = 0; c < 3; ++c) {
        int d = c * 256 + tid;
        float acc = 0.f;
#pragma unroll 8
        for (int k = 0; k < NPART; ++k) acc += wts[k] * base[(size_t)k * DD + d];
        out[b * DD + d] = acc * inv;
    }
}

// ---------------------------------------------------------------------------
extern "C" void kernel_launch(void* const* d_in, const int* in_sizes, int n_in,
                              void* d_out, int out_size, void* d_ws, size_t ws_size,
                              hipStream_t stream) {
    const float* z = (const float*)d_in[0];   // [B,P,D]
    const float* q = (const float*)d_in[1];   // [1,1,D]
    const float* W = (const float*)d_in[2];   // [D,D]
    float* out = (float*)d_out;               // [B,D]

    char* ws = (char*)d_ws;
    float* qw   = (float*)ws;                         // 768 floats
    float* ml   = (float*)(ws + 4096);                // 2048*2 floats
    float* macc = (float*)(ws + 4096 + 32768);        // 2048*768 floats (6.3 MB)

    hipMemsetAsync(qw, 0, DD * sizeof(float), stream);
    dim3 qg(3, 32);
    qw_kernel<<<qg, 256, 0, stream>>>(q, W, qw);
    dim3 fg(BB, SS);
    fused_kernel<<<fg, 256, 0, stream>>>(z, qw, macc, ml);
    reduce_kernel<<<BB, 256, 0, stream>>>(macc, ml, out);
}